// Round 1
// baseline (329.994 us; speedup 1.0000x reference)
//
#include <hip/hip_runtime.h>

// CRF NLL on MI355X.
// feats: [B,T,C] f32, mask: [B,T] i32 (contiguous prefix), tags: [B,T] i32,
// trans: [C,C] f32 (col C-2 and row C-1 masked to -1e5). Output: scalar NLL/B.
//
// Design: one block per batch element (the time scan is strictly sequential).
// 512 threads = 4 "sub" lanes per state j (j = tid>>2). exp(trans) column
// fragments live in registers (32 floats/thread); per step only the 128-float
// p vector round-trips through LDS (broadcast reads). Running-offset trick
// replaces per-step max-reduction: center alpha by column-0's value each step
// (spread across states is bounded ~±20, so exp() is safe in fp32).

#define BB   128
#define TT   512
#define CC   128
#define NTHR 512
#define KPT  32   // CC / 4 sub-lanes

__global__ __launch_bounds__(NTHR) void crf_fused(
    const float* __restrict__ feats,
    const int*   __restrict__ mask,
    const int*   __restrict__ tags,
    const float* __restrict__ trans,
    float*       __restrict__ acc)   // acc[0] = sum forward, acc[1] = sum score
{
    const int b   = blockIdx.x;
    const int tid = threadIdx.x;
    const int j   = tid >> 2;   // state column this thread helps compute
    const int sub = tid & 3;    // which 32-slice of the i-dimension
    const int wid = tid >> 6;

    __shared__ __align__(16) float pbuf[CC];
    __shared__ float cbox;
    __shared__ float wred[8];

    // ---- sequence length (mask is a contiguous prefix; tid spans T exactly) ----
    const int myM = mask[b * TT + tid];
    const int len = __syncthreads_count(myM);

    // ---- gold-path score for this batch element ----
    {
        float sc = 0.0f;
        if (myM) {
            const int tg = tags[b * TT + tid];
            sc += feats[((size_t)(b * TT + tid)) * CC + tg];
            sc += (tid == 0) ? trans[(CC - 2) * CC + tg]                 // START -> tags[0]
                             : trans[tags[b * TT + tid - 1] * CC + tg];  // tags[t-1] -> tags[t]
            const int nm = (tid == TT - 1) ? 0 : mask[b * TT + tid + 1];
            if (!nm) sc += trans[tg * CC + (CC - 1)];                    // last -> STOP
        }
        #pragma unroll
        for (int o = 1; o <= 32; o <<= 1) sc += __shfl_xor(sc, o);
        if ((tid & 63) == 0) wred[wid] = sc;
        __syncthreads();
        if (tid == 0) {
            float s = 0.0f;
            #pragma unroll
            for (int k = 0; k < 8; ++k) s += wred[k];
            atomicAdd(&acc[1], s);
        }
        // thread 0's wred reads complete before it can pass the scan loop's
        // first barrier; wred is not rewritten until after the loop.
    }

    // ---- exp(transitions) fragment into registers: E[k] = exp(trans[sub*32+k][j]) ----
    float E[KPT];
    #pragma unroll
    for (int k = 0; k < KPT; ++k)
        E[k] = __expf(trans[(sub * KPT + k) * CC + j]);

    // ---- forward scan: beta = alpha - S (centered so beta[0] == 0) ----
    float beta = (j == CC - 2) ? 0.0f : -10000.0f;
    float S = 0.0f;
    const float* fb = feats + (size_t)b * TT * CC;

    for (int t = 0; t < len; ++t) {
        const float p = __expf(beta);           // -inf -> 0, -10000 -> 0: safe
        if (sub == 0) pbuf[j] = p;
        __syncthreads();                        // p visible; prev cbox reads done
        const float4* p4 = (const float4*)(pbuf + sub * KPT);
        float d0 = 0.f, d1 = 0.f, d2 = 0.f, d3 = 0.f;
        #pragma unroll
        for (int k = 0; k < KPT / 4; ++k) {
            const float4 v = p4[k];
            d0 = fmaf(E[4 * k + 0], v.x, d0);
            d1 = fmaf(E[4 * k + 1], v.y, d1);
            d2 = fmaf(E[4 * k + 2], v.z, d2);
            d3 = fmaf(E[4 * k + 3], v.w, d3);
        }
        float dot = (d0 + d1) + (d2 + d3);
        dot += __shfl_xor(dot, 1);
        dot += __shfl_xor(dot, 2);
        // START column: all E == 0 -> dot == 0 -> log -> -inf (matches ref's
        // effective -1e5 path: both contribute exactly 0 downstream in fp32).
        const float raw = fb[t * CC + j] + __logf(dot);
        if (tid == 0) cbox = raw;               // column 0 is always finite
        __syncthreads();
        const float c = cbox;
        beta = raw - c;
        S += c;
    }

    // ---- terminal: logsumexp_j(alpha_j + trans[j][STOP]) ----
    const float last = beta + trans[j * CC + (CC - 1)];
    float mx = last;
    #pragma unroll
    for (int o = 1; o <= 32; o <<= 1) mx = fmaxf(mx, __shfl_xor(mx, o));
    if ((tid & 63) == 0) wred[wid] = mx;
    __syncthreads();
    float M = wred[0];
    #pragma unroll
    for (int k = 1; k < 8; ++k) M = fmaxf(M, wred[k]);
    float e = (sub == 0) ? __expf(last - M) : 0.0f;   // count each j once
    #pragma unroll
    for (int o = 1; o <= 32; o <<= 1) e += __shfl_xor(e, o);
    __syncthreads();
    if ((tid & 63) == 0) wred[wid] = e;
    __syncthreads();
    if (tid == 0) {
        float s = 0.0f;
        #pragma unroll
        for (int k = 0; k < 8; ++k) s += wred[k];
        atomicAdd(&acc[0], S + M + __logf(s));
    }
}

__global__ void crf_final(const float* __restrict__ acc, float* __restrict__ out)
{
    out[0] = (acc[0] - acc[1]) * (1.0f / (float)BB);
}

extern "C" void kernel_launch(void* const* d_in, const int* in_sizes, int n_in,
                              void* d_out, int out_size, void* d_ws, size_t ws_size,
                              hipStream_t stream)
{
    const float* feats = (const float*)d_in[0];
    const int*   mask  = (const int*)d_in[1];
    const int*   tags  = (const int*)d_in[2];
    const float* trans = (const float*)d_in[3];
    float* out = (float*)d_out;
    float* acc = (float*)d_ws;

    hipMemsetAsync(acc, 0, 2 * sizeof(float), stream);
    crf_fused<<<BB, NTHR, 0, stream>>>(feats, mask, tags, trans, acc);
    crf_final<<<1, 1, 0, stream>>>(acc, out);
}

// Round 2
// 303.945 us; speedup vs baseline: 1.0857x; 1.0857x over previous
//
#include <hip/hip_runtime.h>

// CRF NLL on MI355X, round 2: latency-optimized sequential scan.
// One block per batch element (scan is sequential in t). 512 threads =
// 64 teams x 8 subs; team jp owns columns j0=2jp, j1=2jp+1; sub owns a
// 16-row slice of i. exp(trans) fragments in registers (32 floats/thread).
// Probability-domain recurrence with 1-step-lagged rescale:
//   u_{t+1}[j] = exp(feat[t,j]) * (sum_i u_t[i] E[i][j]) / c_t,  c_t = u_t[0]
// -> one no-drain barrier per step (asm s_waitcnt lgkmcnt(0); s_barrier),
// feats prefetched PF=4 steps ahead in registers (HBM latency hidden),
// double-buffered 128-float p vector in LDS, bank-conflict-free chunk swizzle.

#define BB   128
#define TT   512
#define CC   128
#define NTHR 512
#define PF   4

typedef float v2f __attribute__((ext_vector_type(2)));

__device__ __forceinline__ void bar_nodrain() {
    // LDS-visibility barrier that does NOT drain vmcnt (global prefetch stays
    // in flight). "memory" clobber stops compiler reordering across it.
    asm volatile("s_waitcnt lgkmcnt(0)\n\ts_barrier" ::: "memory");
}

__global__ __launch_bounds__(NTHR) void crf_fused(
    const float* __restrict__ feats,
    const int*   __restrict__ mask,
    const int*   __restrict__ tags,
    const float* __restrict__ trans,
    float*       __restrict__ acc)   // acc[0] += forward, acc[1] += gold score
{
    const int b   = blockIdx.x;
    const int tid = threadIdx.x;
    const int jp  = tid >> 3;        // team: columns 2jp, 2jp+1
    const int sub = tid & 7;         // 16-row i-slice
    const int j0  = jp * 2;
    const int j1  = j0 + 1;
    const int wid = tid >> 6;

    __shared__ __align__(16) float buf[2][CC];  // double-buffered u vector
    __shared__ float cbox[2];
    __shared__ float wred[8];

    // ---- sequence length (contiguous prefix mask; tid spans T exactly) ----
    const int myM = mask[b * TT + tid];
    const int len = __syncthreads_count(myM);

    // ---- gold-path score (once; off the scan's critical path) ----
    {
        float sc = 0.0f;
        if (myM) {
            const int tg = tags[b * TT + tid];
            sc += feats[((size_t)(b * TT + tid)) * CC + tg];
            sc += (tid == 0) ? trans[(CC - 2) * CC + tg]
                             : trans[tags[b * TT + tid - 1] * CC + tg];
            const int nm = (tid == TT - 1) ? 0 : mask[b * TT + tid + 1];
            if (!nm) sc += trans[tg * CC + (CC - 1)];
        }
        #pragma unroll
        for (int o = 1; o <= 32; o <<= 1) sc += __shfl_xor(sc, o);
        if ((tid & 63) == 0) wred[wid] = sc;
        __syncthreads();
        if (tid == 0) {
            float s = 0.0f;
            #pragma unroll
            for (int k = 0; k < 8; ++k) s += wred[k];
            atomicAdd(&acc[1], s);
        }
        // wred re-used only after the post-loop __syncthreads().
    }

    // ---- E fragments, chunk order swizzled so each wave's 8 distinct 16B
    //      chunks hit 8 distinct bank quads (conflict-free) ----
    const int s2 = sub >> 1;
    int kkA[4];
    v2f E0v[8], E1v[8];
    #pragma unroll
    for (int k = 0; k < 4; ++k) {
        const int kk = (k + s2) & 3;
        kkA[k] = kk;
        const int r = sub * 16 + kk * 4;
        #pragma unroll
        for (int m = 0; m < 2; ++m) {
            const int r0 = r + 2 * m;
            const float2 ta = *(const float2*)&trans[(size_t)(r0    ) * CC + j0];
            const float2 tb = *(const float2*)&trans[(size_t)(r0 + 1) * CC + j0];
            v2f e0, e1;
            e0.x = __expf(ta.x); e0.y = __expf(tb.x);
            e1.x = __expf(ta.y); e1.y = __expf(tb.y);
            E0v[2 * k + m] = e0;
            E1v[2 * k + m] = e1;
        }
    }
    // terminal transition-to-STOP factors
    const float Es0 = __expf(trans[(size_t)j0 * CC + (CC - 1)]);
    const float Es1 = __expf(trans[(size_t)j1 * CC + (CC - 1)]);

    // ---- init: u_0 = 1 at START(126), 0 elsewhere; c_0 = 1 ----
    if (tid < CC) buf[0][tid] = (tid == CC - 2) ? 1.0f : 0.0f;
    if (tid == 0) cbox[0] = 1.0f;

    // ---- feats prefetch (PF deep, rotating registers) ----
    const float* fb = feats + (size_t)b * TT * CC;
    float2 fx[PF];
    #pragma unroll
    for (int k = 0; k < PF; ++k)
        fx[k] = *(const float2*)&fb[(size_t)k * CC + j0];

    const float* pb0 = &buf[0][sub * 16];
    const float* pb1 = &buf[1][sub * 16];

    float S = 0.0f;                          // sum of log(c_t), t < len
    const int lenUp = (len + 3) & ~3;

    for (int tc = 0; tc < lenUp; tc += 4) {
        #pragma unroll
        for (int k = 0; k < 4; ++k) {
            const int t   = tc + k;
            const int par = k & 1;           // == t & 1
            bar_nodrain();                   // buf[par], cbox[par] now visible
            const float c = cbox[par];
            const float4* q = (const float4*)(par ? pb1 : pb0);

            v2f a0 = {0.f, 0.f}, a1 = {0.f, 0.f};
            v2f b0 = {0.f, 0.f}, b1 = {0.f, 0.f};
            #pragma unroll
            for (int kq = 0; kq < 4; ++kq) {
                const float4 P = q[kkA[kq]];
                v2f P01; P01.x = P.x; P01.y = P.y;
                v2f P23; P23.x = P.z; P23.y = P.w;
                a0 = __builtin_elementwise_fma(E0v[2 * kq],     P01, a0);
                a1 = __builtin_elementwise_fma(E0v[2 * kq + 1], P23, a1);
                b0 = __builtin_elementwise_fma(E1v[2 * kq],     P01, b0);
                b1 = __builtin_elementwise_fma(E1v[2 * kq + 1], P23, b1);
            }
            a0 += a1; b0 += b1;
            float s0 = a0.x + a0.y;
            float s1 = b0.x + b0.y;
            #pragma unroll
            for (int o = 1; o <= 4; o <<= 1) {
                s0 += __shfl_xor(s0, o);
                s1 += __shfl_xor(s1, o);
            }

            const float rinv = __builtin_amdgcn_rcpf(c);
            const float e0f  = __expf(fx[k].x);
            const float e1f  = __expf(fx[k].y);
            const float v0   = e0f * s0 * rinv;
            const float v1   = e1f * s1 * rinv;

            // prefetch feats for step t+PF (clamped; identical work each call)
            int tn = t + PF;
            tn = (tn < TT) ? tn : (TT - 1);
            fx[k] = *(const float2*)&fb[(size_t)tn * CC + j0];

            if (t < len) {                   // uniform branch
                S += __logf(c);
                if (sub == 0) {
                    float2 w2; w2.x = v0; w2.y = v1;
                    *(float2*)&buf[par ^ 1][j0] = w2;
                    if (tid == 0) cbox[par ^ 1] = v0;
                }
            }
            // steps t >= len: no writes -> state frozen (padding is a no-op)
        }
    }

    // ---- terminal: log(sum_j u_len[j] * exp(trans[j][STOP])) + S ----
    __syncthreads();                         // full barrier: buf/wred safe
    const float2 uu = *(const float2*)&buf[len & 1][j0];
    float z = (sub == 0) ? (uu.x * Es0 + uu.y * Es1) : 0.0f;
    #pragma unroll
    for (int o = 1; o <= 32; o <<= 1) z += __shfl_xor(z, o);
    if ((tid & 63) == 0) wred[wid] = z;
    __syncthreads();
    if (tid == 0) {
        float s = 0.0f;
        #pragma unroll
        for (int k = 0; k < 8; ++k) s += wred[k];
        atomicAdd(&acc[0], __logf(s) + S);
    }
}

__global__ void crf_final(const float* __restrict__ acc, float* __restrict__ out)
{
    out[0] = (acc[0] - acc[1]) * (1.0f / (float)BB);
}

extern "C" void kernel_launch(void* const* d_in, const int* in_sizes, int n_in,
                              void* d_out, int out_size, void* d_ws, size_t ws_size,
                              hipStream_t stream)
{
    const float* feats = (const float*)d_in[0];
    const int*   mask  = (const int*)d_in[1];
    const int*   tags  = (const int*)d_in[2];
    const float* trans = (const float*)d_in[3];
    float* out = (float*)d_out;
    float* acc = (float*)d_ws;

    hipMemsetAsync(acc, 0, 2 * sizeof(float), stream);
    crf_fused<<<BB, NTHR, 0, stream>>>(feats, mask, tags, trans, acc);
    crf_final<<<1, 1, 0, stream>>>(acc, out);
}